// Round 1
// 372.670 us; speedup vs baseline: 1.0570x; 1.0570x over previous
//
#include <hip/hip_runtime.h>
#include <hip/hip_bf16.h>

using bf16 = __bf16;
typedef __bf16 bf16x4 __attribute__((ext_vector_type(4)));
typedef __bf16 bf16x8 __attribute__((ext_vector_type(8)));
typedef float f32x4 __attribute__((ext_vector_type(4)));

static constexpr int BATCH = 4;
static constexpr int SEQ   = 2048;
static constexpr int DIN   = 512;
static constexpr int NHEAD = 8;
static constexpr int DMID  = 2048;
static constexpr int MROWS = BATCH * SEQ;   // 8192

// ---------------------------------------------------------------------------
// global -> LDS direct DMA, 16 B per lane (global_load_lds_dwordx4).
// LDS dest is wave-uniform base + lane*16 (linear); global src is per-lane.
// ---------------------------------------------------------------------------
__device__ __forceinline__ void gload16(const void* g, void* l)
{
    __builtin_amdgcn_global_load_lds(
        (const __attribute__((address_space(1))) unsigned int*)g,
        (__attribute__((address_space(3))) unsigned int*)l, 16, 0, 0);
}

// ---------------------------------------------------------------------------
// Mask nonzero check (bitwise OR; flag pre-zeroed via hipMemsetAsync).
// ---------------------------------------------------------------------------
__global__ __launch_bounds__(256) void mask_check(const uint4* __restrict__ m,
                                                  int* __restrict__ flag)
{
    const int base = (blockIdx.x * 256 + threadIdx.x) * 4;
    unsigned nz = 0;
    for (int i = 0; i < 4; ++i) {
        const uint4 v = m[base + i];
        nz |= v.x | v.y | v.z | v.w;
    }
    if (nz) atomicOr(flag, 1);
}

// ---------------------------------------------------------------------------
// All six weight transposes (fp32 [R][C] -> bf16 [C][R]) in ONE launch.
// ---------------------------------------------------------------------------
__global__ __launch_bounds__(256) void transpose_weights(
    const float* __restrict__ WQ, const float* __restrict__ WK,
    const float* __restrict__ WV, const float* __restrict__ WO,
    const float* __restrict__ W1, const float* __restrict__ W2,
    bf16* __restrict__ WQt, bf16* __restrict__ WKt, bf16* __restrict__ WVt,
    bf16* __restrict__ WOt, bf16* __restrict__ W1t, bf16* __restrict__ W2t)
{
    __shared__ float tile[32][33];
    const int bid = blockIdx.x;
    const float* in; bf16* out; int ip, op, cx, ry;
    if (bid < 1024) {
        const int w = bid >> 8, idx = bid & 255;
        in  = w == 0 ? WQ  : w == 1 ? WK  : w == 2 ? WV  : WO;
        out = w == 0 ? WQt : w == 1 ? WKt : w == 2 ? WVt : WOt;
        ip = 512; op = 512; cx = idx & 15; ry = idx >> 4;
    } else if (bid < 2048) {
        const int idx = bid - 1024;
        in = W1; out = W1t; ip = 2048; op = 512; cx = idx & 63; ry = idx >> 6;
    } else {
        const int idx = bid - 2048;
        in = W2; out = W2t; ip = 512; op = 2048; cx = idx & 15; ry = idx >> 4;
    }
    const int c0 = cx * 32, r0 = ry * 32;
    const int tx = threadIdx.x & 31, ty = threadIdx.x >> 5;
    for (int i = 0; i < 32; i += 8)
        tile[ty + i][tx] = in[(size_t)(r0 + ty + i) * ip + c0 + tx];
    __syncthreads();
    for (int i = 0; i < 32; i += 8)
        out[(size_t)(c0 + ty + i) * op + r0 + tx] = (bf16)tile[tx][ty + i];
}

// ---------------------------------------------------------------------------
// bf16 [R][C] -> bf16 transposed [C][R].  Grid (C/32, R/32).
// ---------------------------------------------------------------------------
__global__ __launch_bounds__(256) void transpose_b2b(const bf16* __restrict__ in,
                                                     bf16* __restrict__ out,
                                                     int ip, int op)
{
    __shared__ bf16 tile[32][33];
    const int c0 = blockIdx.x * 32;
    const int r0 = blockIdx.y * 32;
    const int tx = threadIdx.x & 31;
    const int ty = threadIdx.x >> 5;
    for (int i = 0; i < 32; i += 8)
        tile[ty + i][tx] = in[(size_t)(r0 + ty + i) * ip + c0 + tx];
    __syncthreads();
    for (int i = 0; i < 32; i += 8)
        out[(size_t)(c0 + ty + i) * op + r0 + tx] = tile[tx][ty + i];
}

// ---------------------------------------------------------------------------
// m97-structure GEMM: C[M,N] = act(A[M,K] @ Bt[N,K]^T), 128x128 tile, BK=64.
// 4 waves (2x2), each owns a 64x64 quadrant; per wave-kstep 16 ds_read_b128
// feed 32 MFMAs (2:1).  B (and A when bf16) staged via global_load_lds w=16
// into linear unpadded [128][64] LDS; fp32-A variant (QKV) reg-stages A with
// the global loads hoisted before the first barrier.
// ---------------------------------------------------------------------------
template <int ACT, bool AF32>
__device__ __forceinline__ void gemm128_body(const void* __restrict__ Ain,
                                             const bf16* __restrict__ Bt,
                                             bf16* __restrict__ C,
                                             int N, int K,
                                             bf16* sA, bf16* sB)
{
    const int t    = threadIdx.x;
    const int lane = t & 63;
    const int wave = t >> 6;
    const int wm   = wave >> 1;
    const int wn   = wave & 1;
    const int lr   = lane & 15;
    const int lq   = lane >> 4;

    const int m0 = blockIdx.y * 128;
    const int n0 = blockIdx.x * 128;

    // staging geometry: one gload16 instruction = 64 lanes x 16B = 8 rows of
    // 64 bf16.  chunk ch = wave*4+i covers rows ch*8..ch*8+7 (16 chunks/tile).
    const int srow = lane >> 3;        // 0..7  row within chunk
    const int scol = (lane & 7) * 8;   // bf16 column offset (16B granule)

    f32x4 acc[4][4] = {};

    for (int k0 = 0; k0 < K; k0 += 64) {
        if constexpr (AF32) {
            // fp32 A: issue global loads BEFORE the barrier (no LDS touch),
            // so their latency hides under the previous k-step's MFMAs.
            const float* Af = (const float*)Ain;
            float4 fa[8];
#pragma unroll
            for (int i = 0; i < 4; ++i) {
                const float* p = Af + (size_t)(m0 + (wave * 4 + i) * 8 + srow) * K + k0 + scol;
                fa[2 * i]     = *reinterpret_cast<const float4*>(p);
                fa[2 * i + 1] = *reinterpret_cast<const float4*>(p + 4);
            }
            if (k0) __syncthreads();
#pragma unroll
            for (int i = 0; i < 4; ++i) {
                const int ch = wave * 4 + i;
                gload16(Bt + (size_t)(n0 + ch * 8 + srow) * K + k0 + scol, sB + ch * 512);
            }
#pragma unroll
            for (int i = 0; i < 4; ++i) {
                const int r = (wave * 4 + i) * 8 + srow;
                const float4 a = fa[2 * i], b = fa[2 * i + 1];
                bf16x8 h;
                h[0] = (bf16)a.x; h[1] = (bf16)a.y; h[2] = (bf16)a.z; h[3] = (bf16)a.w;
                h[4] = (bf16)b.x; h[5] = (bf16)b.y; h[6] = (bf16)b.z; h[7] = (bf16)b.w;
                *reinterpret_cast<bf16x8*>(&sA[r * 64 + scol]) = h;   // contiguous 1 KB/instr
            }
        } else {
            const bf16* Ab = (const bf16*)Ain;
            if (k0) __syncthreads();
#pragma unroll
            for (int i = 0; i < 4; ++i) {
                const int ch = wave * 4 + i;
                const int r  = ch * 8 + srow;
                gload16(Ab + (size_t)(m0 + r) * K + k0 + scol, sA + ch * 512);
                gload16(Bt + (size_t)(n0 + r) * K + k0 + scol, sB + ch * 512);
            }
        }
        __syncthreads();

#pragma unroll
        for (int kk = 0; kk < 2; ++kk) {
            bf16x8 af[4], bfr[4];
#pragma unroll
            for (int x = 0; x < 4; ++x) {
                af[x]  = *reinterpret_cast<const bf16x8*>(&sA[(wm * 64 + x * 16 + lr) * 64 + kk * 32 + lq * 8]);
                bfr[x] = *reinterpret_cast<const bf16x8*>(&sB[(wn * 64 + x * 16 + lr) * 64 + kk * 32 + lq * 8]);
            }
#pragma unroll
            for (int m = 0; m < 4; ++m)
#pragma unroll
                for (int n = 0; n < 4; ++n)
                    acc[m][n] = __builtin_amdgcn_mfma_f32_16x16x32_bf16(af[m], bfr[n], acc[m][n], 0, 0, 0);
        }
    }

#pragma unroll
    for (int n = 0; n < 4; ++n) {
        const int col = n0 + wn * 64 + n * 16 + lr;
#pragma unroll
        for (int m = 0; m < 4; ++m) {
            const int rowb = m0 + wm * 64 + m * 16 + lq * 4;
#pragma unroll
            for (int j = 0; j < 4; ++j) {
                float v = acc[m][n][j];
                if (ACT == 1) v = v > 0.f ? v : 0.f;
                C[(size_t)(rowb + j) * N + col] = (bf16)v;
            }
        }
    }
}

template <int ACT>
__global__ __launch_bounds__(256) void gemm128(const bf16* __restrict__ A,
                                               const bf16* __restrict__ Bt,
                                               bf16* __restrict__ C,
                                               int N, int K)
{
    __shared__ bf16 sA[128 * 64];
    __shared__ bf16 sB[128 * 64];
    gemm128_body<ACT, false>(A, Bt, C, N, K, sA, sB);
}

// QKV projection: three fp32-A GEMMs batched on blockIdx.z.
__global__ __launch_bounds__(256) void gemm128_qkv(const float* __restrict__ q,
                                                   const float* __restrict__ k,
                                                   const float* __restrict__ v,
                                                   const bf16* __restrict__ WQt,
                                                   const bf16* __restrict__ WKt,
                                                   const bf16* __restrict__ WVt,
                                                   bf16* __restrict__ Qb,
                                                   bf16* __restrict__ Kb,
                                                   bf16* __restrict__ Vb)
{
    __shared__ bf16 sA[128 * 64];
    __shared__ bf16 sB[128 * 64];
    const void* A  = blockIdx.z == 0 ? (const void*)q : blockIdx.z == 1 ? (const void*)k : (const void*)v;
    const bf16* Bt = blockIdx.z == 0 ? WQt : blockIdx.z == 1 ? WKt : WVt;
    bf16*       C  = blockIdx.z == 0 ? Qb  : blockIdx.z == 1 ? Kb  : Vb;
    gemm128_body<0, true>(A, Bt, C, DIN, DIN, sA, sB);
}

// ---------------------------------------------------------------------------
// Flash attention (MFMA), q-tile 64, max-free softmax, runtime mask-skip.
// UNCHANGED this round (isolating the GEMM structural swap).
// Tripwire: dur ~89.6 us, WRITE_SIZE 8.2 MB.
// ---------------------------------------------------------------------------
__global__ __launch_bounds__(256) void attn_kernel(const bf16* __restrict__ Qb,
                                                   const bf16* __restrict__ Kb,
                                                   const bf16* __restrict__ Vt,
                                                   const float* __restrict__ mask,
                                                   bf16* __restrict__ O,
                                                   const int* __restrict__ mzf)
{
    const int bi   = blockIdx.x;
    const int xcd  = bi & 7;
    const int slot = bi >> 3;
    const int pair = xcd * 4 + (slot >> 5);
    const int qt   = slot & 31;
    const int h    = pair >> 2;
    const int b    = pair & 3;

    const int t    = threadIdx.x;
    const int lane = t & 63;
    const int wave = t >> 6;
    const int lr   = lane & 15;
    const int lq   = lane >> 4;
    const int q0   = qt * 64;
    const bool useM = (*mzf != 0);

    __shared__ bf16 sK[64 * 72];
    __shared__ bf16 sV[64 * 72];
    __shared__ bf16 sP[4][16 * 72];
    __shared__ bf16 sM[64 * 68];

    const int  qrow = q0 + wave * 16 + lr;
    const bf16* qp  = Qb + (size_t)(b * SEQ + qrow) * DIN + h * 64 + lq * 8;
    const bf16x8 qf0 = *reinterpret_cast<const bf16x8*>(qp);
    const bf16x8 qf1 = *reinterpret_cast<const bf16x8*>(qp + 32);

    f32x4 o[4] = {};
    f32x4 lrow = {};

    const int sr = t >> 2;
    const int sc = (t & 3) << 3;

    const bf16*  kbase = Kb + (size_t)(b * SEQ) * DIN + h * 64;
    const bf16*  vbase = Vt + (size_t)(h * 64 + sr) * MROWS + b * SEQ;
    const float* mbase = mask + ((size_t)b * SEQ + q0) * SEQ;

    constexpr float L2E = 1.4426950408889634f;
    constexpr float SCL = 0.125f * L2E;
    const bf16x8 ones = {(bf16)1.f, (bf16)1.f, (bf16)1.f, (bf16)1.f,
                         (bf16)1.f, (bf16)1.f, (bf16)1.f, (bf16)1.f};

    int4 kr0 = *reinterpret_cast<const int4*>(kbase + (size_t)sr * DIN + sc);
    int4 kr1 = *reinterpret_cast<const int4*>(kbase + (size_t)sr * DIN + sc + 32);
    int4 vr0 = *reinterpret_cast<const int4*>(vbase + sc);
    int4 vr1 = *reinterpret_cast<const int4*>(vbase + sc + 32);

    for (int tile = 0; tile < SEQ / 64; ++tile) {
        if (tile) __syncthreads();

        *reinterpret_cast<int4*>(&sK[sr * 72 + sc])      = kr0;
        *reinterpret_cast<int4*>(&sK[sr * 72 + sc + 32]) = kr1;
        *reinterpret_cast<int4*>(&sV[sr * 72 + sc])      = vr0;
        *reinterpret_cast<int4*>(&sV[sr * 72 + sc + 32]) = vr1;
        if (useM) {
            const int k0 = tile * 64;
            for (int i = 0; i < 4; ++i) {
                const int idx = t + 256 * i;
                const float4 mr = *reinterpret_cast<const float4*>(
                    mbase + (size_t)(idx >> 4) * SEQ + k0 + (idx & 15) * 4);
                bf16x4 mv;
                mv[0] = (bf16)(mr.x * L2E); mv[1] = (bf16)(mr.y * L2E);
                mv[2] = (bf16)(mr.z * L2E); mv[3] = (bf16)(mr.w * L2E);
                *reinterpret_cast<bf16x4*>(&sM[(idx >> 4) * 68 + (idx & 15) * 4]) = mv;
            }
        }

        if (tile + 1 < SEQ / 64) {
            const int k0 = (tile + 1) * 64;
            kr0 = *reinterpret_cast<const int4*>(kbase + (size_t)(k0 + sr) * DIN + sc);
            kr1 = *reinterpret_cast<const int4*>(kbase + (size_t)(k0 + sr) * DIN + sc + 32);
            vr0 = *reinterpret_cast<const int4*>(vbase + k0 + sc);
            vr1 = *reinterpret_cast<const int4*>(vbase + k0 + sc + 32);
        }
        __syncthreads();

        f32x4 sf[4] = {};
        for (int s = 0; s < 2; ++s) {
            const bf16x8 qf = s ? qf1 : qf0;
            for (int ni = 0; ni < 4; ++ni) {
                bf16x8 kf = *reinterpret_cast<const bf16x8*>(&sK[(ni * 16 + lr) * 72 + s * 32 + lq * 8]);
                sf[ni] = __builtin_amdgcn_mfma_f32_16x16x32_bf16(qf, kf, sf[ni], 0, 0, 0);
            }
        }

        if (useM) {
            for (int j = 0; j < 4; ++j) {
                const int mr2 = (wave * 16 + lq * 4 + j) * 68;
                for (int ni = 0; ni < 4; ++ni) {
                    const float mval = (float)sM[mr2 + ni * 16 + lr];
                    sP[wave][(lq * 4 + j) * 72 + ni * 16 + lr] = (bf16)exp2f(sf[ni][j] * SCL + mval);
                }
            }
        } else {
            for (int j = 0; j < 4; ++j)
                for (int ni = 0; ni < 4; ++ni)
                    sP[wave][(lq * 4 + j) * 72 + ni * 16 + lr] = (bf16)exp2f(sf[ni][j] * SCL);
        }

        f32x4 rs = {};
        for (int s = 0; s < 2; ++s) {
            bf16x8 pf = *reinterpret_cast<const bf16x8*>(&sP[wave][lr * 72 + s * 32 + lq * 8]);
            rs = __builtin_amdgcn_mfma_f32_16x16x32_bf16(pf, ones, rs, 0, 0, 0);
            for (int ni = 0; ni < 4; ++ni) {
                bf16x8 vf = *reinterpret_cast<const bf16x8*>(&sV[(ni * 16 + lr) * 72 + s * 32 + lq * 8]);
                o[ni] = __builtin_amdgcn_mfma_f32_16x16x32_bf16(pf, vf, o[ni], 0, 0, 0);
            }
        }
        for (int j = 0; j < 4; ++j)
            lrow[j] += rs[j];
    }

    for (int ni = 0; ni < 4; ++ni)
        for (int j = 0; j < 4; ++j) {
            const int row = q0 + wave * 16 + lq * 4 + j;
            const int col = h * 64 + ni * 16 + lr;
            O[(size_t)(b * SEQ + row) * DIN + col] = (bf16)(o[ni][j] / lrow[j]);
        }
}

// ---------------------------------------------------------------------------
// Fused residual add + LayerNorm over D=512. X fp32, Y bf16.
// ---------------------------------------------------------------------------
__global__ __launch_bounds__(256) void add_ln(const float* __restrict__ X,
                                              const bf16* __restrict__ Y,
                                              bf16* __restrict__ Ob,
                                              float* __restrict__ Of)
{
    const int row  = blockIdx.x * 4 + (threadIdx.x >> 6);
    const int lane = threadIdx.x & 63;
    const size_t base = (size_t)row * DIN + lane * 8;
    const float4 x0 = *reinterpret_cast<const float4*>(X + base);
    const float4 x1 = *reinterpret_cast<const float4*>(X + base + 4);
    const bf16x8 yv = *reinterpret_cast<const bf16x8*>(Y + base);
    float v[8] = {x0.x, x0.y, x0.z, x0.w, x1.x, x1.y, x1.z, x1.w};
    float s = 0.f;
    for (int i = 0; i < 8; ++i) { v[i] += (float)yv[i]; s += v[i]; }
    for (int off = 1; off < 64; off <<= 1) s += __shfl_xor(s, off);
    const float mu = s * (1.f / DIN);
    float var = 0.f;
    for (int i = 0; i < 8; ++i) { const float d = v[i] - mu; var += d * d; }
    for (int off = 1; off < 64; off <<= 1) var += __shfl_xor(var, off);
    const float rstd = rsqrtf(var * (1.f / DIN) + 1e-5f);
    float r[8];
    for (int i = 0; i < 8; ++i) r[i] = (v[i] - mu) * rstd;
    if (Ob) {
        bf16x8 ov;
        for (int i = 0; i < 8; ++i) ov[i] = (bf16)r[i];
        *reinterpret_cast<bf16x8*>(Ob + base) = ov;
    }
    if (Of) {
        *reinterpret_cast<float4*>(Of + base)     = make_float4(r[0], r[1], r[2], r[3]);
        *reinterpret_cast<float4*>(Of + base + 4) = make_float4(r[4], r[5], r[6], r[7]);
    }
}

// ---------------------------------------------------------------------------
extern "C" void kernel_launch(void* const* d_in, const int* in_sizes, int n_in,
                              void* d_out, int out_size, void* d_ws, size_t ws_size,
                              hipStream_t stream)
{
    const float* query = (const float*)d_in[0];
    const float* key   = (const float*)d_in[1];
    const float* value = (const float*)d_in[2];
    const float* mask  = (const float*)d_in[3];
    const float* WQ    = (const float*)d_in[4];
    const float* WK    = (const float*)d_in[5];
    const float* WV    = (const float*)d_in[6];
    const float* WO    = (const float*)d_in[7];
    const float* W1    = (const float*)d_in[8];
    const float* W2    = (const float*)d_in[9];

    char* w = (char*)d_ws;
    size_t off = 0;
    auto carve2 = [&](size_t elems) { bf16* p = (bf16*)(w + off); off += elems * 2; return p; };
    auto carve4 = [&](size_t elems) { float* p = (float*)(w + off); off += elems * 4; return p; };

    bf16* Qb    = carve2((size_t)MROWS * DIN);
    bf16* Kb    = carve2((size_t)MROWS * DIN);
    bf16* Vb    = carve2((size_t)MROWS * DIN);
    bf16* Vt    = carve2((size_t)MROWS * DIN);
    bf16* Mid   = carve2((size_t)MROWS * DMID);
    float* Ln1f = carve4((size_t)MROWS * DIN);
    bf16* WQt   = carve2((size_t)DIN * DIN);
    bf16* WKt   = carve2((size_t)DIN * DIN);
    bf16* WVt   = carve2((size_t)DIN * DIN);
    bf16* WOt   = carve2((size_t)DIN * DIN);
    bf16* W1t   = carve2((size_t)DIN * DMID);
    bf16* W2t   = carve2((size_t)DMID * DIN);
    int*  mzf   = (int*)(w + off); off += 16;
    if (off > ws_size) return;

    // aliases of dead buffers:
    bf16* Ob   = Vb;   // attn output   (Vb dead after Vt transpose)
    bf16* Two  = Qb;   // WO output     (Qb dead after attention)
    bf16* Ln1b = Kb;   // LN1 bf16      (Kb dead after attention)
    bf16* F2   = Vt;   // FFN output    (Vt dead after attention)

    const dim3 blk(256);

    // mask-zero detection
    hipMemsetAsync(mzf, 0, 4, stream);
    mask_check<<<dim3(4096), blk, 0, stream>>>((const uint4*)mask, mzf);

    // all six weight cast+transposes in one launch
    transpose_weights<<<dim3(3072), blk, 0, stream>>>(WQ, WK, WV, WO, W1, W2,
                                                      WQt, WKt, WVt, WOt, W1t, W2t);

    // Q/K/V projections: m97-structure GEMM, fp32-A reg-staged, one launch
    gemm128_qkv<<<dim3(DIN / 128, MROWS / 128, 3), blk, 0, stream>>>(query, key, value,
                                                                     WQt, WKt, WVt, Qb, Kb, Vb);

    // V -> Vt[h*64+d][b*L+l]
    transpose_b2b<<<dim3(DIN / 32, MROWS / 32), blk, 0, stream>>>(Vb, Vt, DIN, MROWS);

    // attention (q-tile 64, XCD-swizzled flat grid, K/V prefetch) — unchanged
    attn_kernel<<<dim3(1024), blk, 0, stream>>>(Qb, Kb, Vt, mask, Ob, mzf);

    // output projection + residual + LN (keep fp32 copy for residual 2)
    gemm128<0><<<dim3(DIN / 128, MROWS / 128), blk, 0, stream>>>(Ob, WOt, Two, DIN, DIN);
    add_ln<<<dim3(MROWS / 4), blk, 0, stream>>>(query, Two, Ln1b, Ln1f);

    // FFN
    gemm128<1><<<dim3(DMID / 128, MROWS / 128), blk, 0, stream>>>(Ln1b, W1t, Mid, DMID, DIN);
    gemm128<0><<<dim3(DIN / 128, MROWS / 128), blk, 0, stream>>>(Mid, W2t, F2, DIN, DMID);

    // final residual + LN -> fp32 output
    add_ln<<<dim3(MROWS / 4), blk, 0, stream>>>(Ln1f, F2, (bf16*)nullptr, (float*)d_out);
}

// Round 3
// 367.621 us; speedup vs baseline: 1.0715x; 1.0137x over previous
//
#include <hip/hip_runtime.h>
#include <hip/hip_bf16.h>

using bf16 = __bf16;
typedef __bf16 bf16x4 __attribute__((ext_vector_type(4)));
typedef __bf16 bf16x8 __attribute__((ext_vector_type(8)));
typedef float f32x4 __attribute__((ext_vector_type(4)));

static constexpr int BATCH = 4;
static constexpr int SEQ   = 2048;
static constexpr int DIN   = 512;
static constexpr int NHEAD = 8;
static constexpr int DMID  = 2048;
static constexpr int MROWS = BATCH * SEQ;   // 8192

// ---------------------------------------------------------------------------
// global -> LDS direct DMA, 16 B per lane (global_load_lds_dwordx4).
// ---------------------------------------------------------------------------
__device__ __forceinline__ void gload16(const void* g, void* l)
{
    __builtin_amdgcn_global_load_lds(
        (const __attribute__((address_space(1))) unsigned int*)g,
        (__attribute__((address_space(3))) unsigned int*)l, 16, 0, 0);
}

// ---------------------------------------------------------------------------
// Mask nonzero check (bitwise OR; flag pre-zeroed via hipMemsetAsync).
// ---------------------------------------------------------------------------
__global__ __launch_bounds__(256) void mask_check(const uint4* __restrict__ m,
                                                  int* __restrict__ flag)
{
    const int base = (blockIdx.x * 256 + threadIdx.x) * 4;
    unsigned nz = 0;
    for (int i = 0; i < 4; ++i) {
        const uint4 v = m[base + i];
        nz |= v.x | v.y | v.z | v.w;
    }
    if (nz) atomicOr(flag, 1);
}

// ---------------------------------------------------------------------------
// All six weight transposes (fp32 [R][C] -> bf16 [C][R]) in ONE launch.
// ---------------------------------------------------------------------------
__global__ __launch_bounds__(256) void transpose_weights(
    const float* __restrict__ WQ, const float* __restrict__ WK,
    const float* __restrict__ WV, const float* __restrict__ WO,
    const float* __restrict__ W1, const float* __restrict__ W2,
    bf16* __restrict__ WQt, bf16* __restrict__ WKt, bf16* __restrict__ WVt,
    bf16* __restrict__ WOt, bf16* __restrict__ W1t, bf16* __restrict__ W2t)
{
    __shared__ float tile[32][33];
    const int bid = blockIdx.x;
    const float* in; bf16* out; int ip, op, cx, ry;
    if (bid < 1024) {
        const int w = bid >> 8, idx = bid & 255;
        in  = w == 0 ? WQ  : w == 1 ? WK  : w == 2 ? WV  : WO;
        out = w == 0 ? WQt : w == 1 ? WKt : w == 2 ? WVt : WOt;
        ip = 512; op = 512; cx = idx & 15; ry = idx >> 4;
    } else if (bid < 2048) {
        const int idx = bid - 1024;
        in = W1; out = W1t; ip = 2048; op = 512; cx = idx & 63; ry = idx >> 6;
    } else {
        const int idx = bid - 2048;
        in = W2; out = W2t; ip = 512; op = 2048; cx = idx & 15; ry = idx >> 4;
    }
    const int c0 = cx * 32, r0 = ry * 32;
    const int tx = threadIdx.x & 31, ty = threadIdx.x >> 5;
    for (int i = 0; i < 32; i += 8)
        tile[ty + i][tx] = in[(size_t)(r0 + ty + i) * ip + c0 + tx];
    __syncthreads();
    for (int i = 0; i < 32; i += 8)
        out[(size_t)(c0 + ty + i) * op + r0 + tx] = (bf16)tile[tx][ty + i];
}

// ---------------------------------------------------------------------------
// bf16 [R][C] -> bf16 transposed [C][R].  Grid (C/32, R/32).
// ---------------------------------------------------------------------------
__global__ __launch_bounds__(256) void transpose_b2b(const bf16* __restrict__ in,
                                                     bf16* __restrict__ out,
                                                     int ip, int op)
{
    __shared__ bf16 tile[32][33];
    const int c0 = blockIdx.x * 32;
    const int r0 = blockIdx.y * 32;
    const int tx = threadIdx.x & 31;
    const int ty = threadIdx.x >> 5;
    for (int i = 0; i < 32; i += 8)
        tile[ty + i][tx] = in[(size_t)(r0 + ty + i) * ip + c0 + tx];
    __syncthreads();
    for (int i = 0; i < 32; i += 8)
        out[(size_t)(c0 + ty + i) * op + r0 + tx] = tile[tx][ty + i];
}

// ---------------------------------------------------------------------------
// 128x128-tile GEMM (m97 structure), for large-N shapes (W1). BK=64, 4 waves.
// ---------------------------------------------------------------------------
template <int ACT>
__global__ __launch_bounds__(256) void gemm128(const bf16* __restrict__ A,
                                               const bf16* __restrict__ Bt,
                                               bf16* __restrict__ C,
                                               int N, int K)
{
    __shared__ bf16 sA[128 * 64];
    __shared__ bf16 sB[128 * 64];

    const int t    = threadIdx.x;
    const int lane = t & 63;
    const int wave = t >> 6;
    const int wm   = wave >> 1;
    const int wn   = wave & 1;
    const int lr   = lane & 15;
    const int lq   = lane >> 4;

    const int m0 = blockIdx.y * 128;
    const int n0 = blockIdx.x * 128;

    const int srow = lane >> 3;
    const int scol = (lane & 7) * 8;

    f32x4 acc[4][4] = {};

    for (int k0 = 0; k0 < K; k0 += 64) {
        if (k0) __syncthreads();
#pragma unroll
        for (int i = 0; i < 4; ++i) {
            const int ch = wave * 4 + i;
            const int r  = ch * 8 + srow;
            gload16(A  + (size_t)(m0 + r) * K + k0 + scol, sA + ch * 512);
            gload16(Bt + (size_t)(n0 + r) * K + k0 + scol, sB + ch * 512);
        }
        __syncthreads();

#pragma unroll
        for (int kk = 0; kk < 2; ++kk) {
            bf16x8 af[4], bfr[4];
#pragma unroll
            for (int x = 0; x < 4; ++x) {
                af[x]  = *reinterpret_cast<const bf16x8*>(&sA[(wm * 64 + x * 16 + lr) * 64 + kk * 32 + lq * 8]);
                bfr[x] = *reinterpret_cast<const bf16x8*>(&sB[(wn * 64 + x * 16 + lr) * 64 + kk * 32 + lq * 8]);
            }
#pragma unroll
            for (int m = 0; m < 4; ++m)
#pragma unroll
                for (int n = 0; n < 4; ++n)
                    acc[m][n] = __builtin_amdgcn_mfma_f32_16x16x32_bf16(af[m], bfr[n], acc[m][n], 0, 0, 0);
        }
    }

#pragma unroll
    for (int n = 0; n < 4; ++n) {
        const int col = n0 + wn * 64 + n * 16 + lr;
#pragma unroll
        for (int m = 0; m < 4; ++m) {
            const int rowb = m0 + wm * 64 + m * 16 + lq * 4;
#pragma unroll
            for (int j = 0; j < 4; ++j) {
                float v = acc[m][n][j];
                if (ACT == 1) v = v > 0.f ? v : 0.f;
                C[(size_t)(rowb + j) * N + col] = (bf16)v;
            }
        }
    }
}

// ---------------------------------------------------------------------------
// 64x128-tile GEMM for skinny-N shapes (WO, W2, QKV): grid 2-6 blocks/CU so
// the global_load_lds drain overlaps across blocks (128-tile gave 1 blk/CU).
// 4 waves side-by-side (each 64x32); per wave-kstep 12 ds_read_b128 : 16 MFMA.
// ---------------------------------------------------------------------------
template <int ACT, bool AF32>
__device__ __forceinline__ void gemm64_body(const void* __restrict__ Ain,
                                            const bf16* __restrict__ Bt,
                                            bf16* __restrict__ C,
                                            int N, int K,
                                            bf16* sA, bf16* sB)
{
    const int t    = threadIdx.x;
    const int lane = t & 63;
    const int wave = t >> 6;         // wn = wave: 32-col strip
    const int lr   = lane & 15;
    const int lq   = lane >> 4;

    const int m0 = blockIdx.y * 64;
    const int n0 = blockIdx.x * 128;

    const int srow = lane >> 3;
    const int scol = (lane & 7) * 8;

    f32x4 acc[4][2] = {};

    for (int k0 = 0; k0 < K; k0 += 64) {
        if constexpr (AF32) {
            const float* Af = (const float*)Ain;
            float4 fa[4];
#pragma unroll
            for (int i = 0; i < 2; ++i) {
                const float* p = Af + (size_t)(m0 + (wave * 2 + i) * 8 + srow) * K + k0 + scol;
                fa[2 * i]     = *reinterpret_cast<const float4*>(p);
                fa[2 * i + 1] = *reinterpret_cast<const float4*>(p + 4);
            }
            if (k0) __syncthreads();
#pragma unroll
            for (int i = 0; i < 4; ++i) {
                const int ch = wave * 4 + i;
                gload16(Bt + (size_t)(n0 + ch * 8 + srow) * K + k0 + scol, sB + ch * 512);
            }
#pragma unroll
            for (int i = 0; i < 2; ++i) {
                const int r = (wave * 2 + i) * 8 + srow;
                const float4 a = fa[2 * i], b = fa[2 * i + 1];
                bf16x8 hh;
                hh[0] = (bf16)a.x; hh[1] = (bf16)a.y; hh[2] = (bf16)a.z; hh[3] = (bf16)a.w;
                hh[4] = (bf16)b.x; hh[5] = (bf16)b.y; hh[6] = (bf16)b.z; hh[7] = (bf16)b.w;
                *reinterpret_cast<bf16x8*>(&sA[r * 64 + scol]) = hh;
            }
        } else {
            const bf16* Ab = (const bf16*)Ain;
            if (k0) __syncthreads();
#pragma unroll
            for (int i = 0; i < 2; ++i) {
                const int ch = wave * 2 + i;
                gload16(Ab + (size_t)(m0 + ch * 8 + srow) * K + k0 + scol, sA + ch * 512);
            }
#pragma unroll
            for (int i = 0; i < 4; ++i) {
                const int ch = wave * 4 + i;
                gload16(Bt + (size_t)(n0 + ch * 8 + srow) * K + k0 + scol, sB + ch * 512);
            }
        }
        __syncthreads();

#pragma unroll
        for (int kk = 0; kk < 2; ++kk) {
            bf16x8 af[4], bfr[2];
#pragma unroll
            for (int x = 0; x < 4; ++x)
                af[x] = *reinterpret_cast<const bf16x8*>(&sA[(x * 16 + lr) * 64 + kk * 32 + lq * 8]);
#pragma unroll
            for (int n = 0; n < 2; ++n)
                bfr[n] = *reinterpret_cast<const bf16x8*>(&sB[(wave * 32 + n * 16 + lr) * 64 + kk * 32 + lq * 8]);
#pragma unroll
            for (int m = 0; m < 4; ++m)
#pragma unroll
                for (int n = 0; n < 2; ++n)
                    acc[m][n] = __builtin_amdgcn_mfma_f32_16x16x32_bf16(af[m], bfr[n], acc[m][n], 0, 0, 0);
        }
    }

#pragma unroll
    for (int n = 0; n < 2; ++n) {
        const int col = n0 + wave * 32 + n * 16 + lr;
#pragma unroll
        for (int m = 0; m < 4; ++m) {
            const int rowb = m0 + m * 16 + lq * 4;
#pragma unroll
            for (int j = 0; j < 4; ++j) {
                float v = acc[m][n][j];
                if (ACT == 1) v = v > 0.f ? v : 0.f;
                C[(size_t)(rowb + j) * N + col] = (bf16)v;
            }
        }
    }
}

template <int ACT>
__global__ __launch_bounds__(256) void gemm64(const bf16* __restrict__ A,
                                              const bf16* __restrict__ Bt,
                                              bf16* __restrict__ C,
                                              int N, int K)
{
    __shared__ bf16 sA[64 * 64];
    __shared__ bf16 sB[128 * 64];
    gemm64_body<ACT, false>(A, Bt, C, N, K, sA, sB);
}

__global__ __launch_bounds__(256) void gemm64_qkv(const float* __restrict__ q,
                                                  const float* __restrict__ k,
                                                  const float* __restrict__ v,
                                                  const bf16* __restrict__ WQt,
                                                  const bf16* __restrict__ WKt,
                                                  const bf16* __restrict__ WVt,
                                                  bf16* __restrict__ Qb,
                                                  bf16* __restrict__ Kb,
                                                  bf16* __restrict__ Vb)
{
    __shared__ bf16 sA[64 * 64];
    __shared__ bf16 sB[128 * 64];
    const void* A  = blockIdx.z == 0 ? (const void*)q : blockIdx.z == 1 ? (const void*)k : (const void*)v;
    const bf16* Bt = blockIdx.z == 0 ? WQt : blockIdx.z == 1 ? WKt : WVt;
    bf16*       C  = blockIdx.z == 0 ? Qb  : blockIdx.z == 1 ? Kb  : Vb;
    gemm64_body<0, true>(A, Bt, C, DIN, DIN, sA, sB);
}

// ---------------------------------------------------------------------------
// Flash attention (MFMA), max-free softmax, runtime mask-skip.
// Each wave owns 32 q-rows (two 16-row groups); the 8 K fragments and 8 V
// fragments are read from LDS ONCE into registers and reused across both
// q-groups -> per-q-row LDS-pipe traffic drops ~0.6x (kernel was
// LDS-throughput-bound).  Q-tile 128, grid 512 (=2 blk/CU, LDS 54.3 KB).
// Softmax math / layouts / staging identical to the verified version.
// ---------------------------------------------------------------------------
__global__ __launch_bounds__(256) void attn_kernel(const bf16* __restrict__ Qb,
                                                   const bf16* __restrict__ Kb,
                                                   const bf16* __restrict__ Vt,
                                                   const float* __restrict__ mask,
                                                   bf16* __restrict__ O,
                                                   const int* __restrict__ mzf)
{
    // XCD swizzle: all 16 q-tiles of one (b,h) land on one XCD.
    const int bi   = blockIdx.x;
    const int xcd  = bi & 7;
    const int slot = bi >> 3;                 // 0..63
    const int pair = xcd * 4 + (slot >> 4);   // 0..31
    const int qt   = slot & 15;               // 0..15
    const int h    = pair >> 2;
    const int b    = pair & 3;

    const int t    = threadIdx.x;
    const int lane = t & 63;
    const int wave = t >> 6;
    const int lr   = lane & 15;
    const int lq   = lane >> 4;
    const int q0   = qt * 128;
    const bool useM = (*mzf != 0);

    __shared__ bf16 sK[64 * 72];
    __shared__ bf16 sV[64 * 72];
    __shared__ bf16 sP[4][32 * 72];
    __shared__ bf16 sM[128 * 68];

    // Q fragments: 2 q-groups x 2 k-halves
    bf16x8 qf[2][2];
#pragma unroll
    for (int g = 0; g < 2; ++g) {
        const int qrow = q0 + wave * 32 + g * 16 + lr;
        const bf16* qp = Qb + (size_t)(b * SEQ + qrow) * DIN + h * 64 + lq * 8;
        qf[g][0] = *reinterpret_cast<const bf16x8*>(qp);
        qf[g][1] = *reinterpret_cast<const bf16x8*>(qp + 32);
    }

    f32x4 o[2][4] = {};
    f32x4 lrow[2] = {};

    const int sr = t >> 2;
    const int sc = (t & 3) << 3;

    const bf16*  kbase = Kb + (size_t)(b * SEQ) * DIN + h * 64;
    const bf16*  vbase = Vt + (size_t)(h * 64 + sr) * MROWS + b * SEQ;
    const float* mbase = mask + ((size_t)b * SEQ + q0) * SEQ;

    constexpr float L2E = 1.4426950408889634f;
    constexpr float SCL = 0.125f * L2E;
    const bf16x8 ones = {(bf16)1.f, (bf16)1.f, (bf16)1.f, (bf16)1.f,
                         (bf16)1.f, (bf16)1.f, (bf16)1.f, (bf16)1.f};

    // prefetch tile 0 into registers
    int4 kr0 = *reinterpret_cast<const int4*>(kbase + (size_t)sr * DIN + sc);
    int4 kr1 = *reinterpret_cast<const int4*>(kbase + (size_t)sr * DIN + sc + 32);
    int4 vr0 = *reinterpret_cast<const int4*>(vbase + sc);
    int4 vr1 = *reinterpret_cast<const int4*>(vbase + sc + 32);

    for (int tile = 0; tile < SEQ / 64; ++tile) {
        if (tile) __syncthreads();

        *reinterpret_cast<int4*>(&sK[sr * 72 + sc])      = kr0;
        *reinterpret_cast<int4*>(&sK[sr * 72 + sc + 32]) = kr1;
        *reinterpret_cast<int4*>(&sV[sr * 72 + sc])      = vr0;
        *reinterpret_cast<int4*>(&sV[sr * 72 + sc + 32]) = vr1;
        if (useM) {
            const int k0 = tile * 64;
#pragma unroll
            for (int i = 0; i < 8; ++i) {
                const int idx = t + 256 * i;          // 0..2047 -> 128 rows x 16 quads
                const float4 mr = *reinterpret_cast<const float4*>(
                    mbase + (size_t)(idx >> 4) * SEQ + k0 + (idx & 15) * 4);
                bf16x4 mv;
                mv[0] = (bf16)(mr.x * L2E); mv[1] = (bf16)(mr.y * L2E);
                mv[2] = (bf16)(mr.z * L2E); mv[3] = (bf16)(mr.w * L2E);
                *reinterpret_cast<bf16x4*>(&sM[(idx >> 4) * 68 + (idx & 15) * 4]) = mv;
            }
        }

        if (tile + 1 < SEQ / 64) {
            const int k0 = (tile + 1) * 64;
            kr0 = *reinterpret_cast<const int4*>(kbase + (size_t)(k0 + sr) * DIN + sc);
            kr1 = *reinterpret_cast<const int4*>(kbase + (size_t)(k0 + sr) * DIN + sc + 32);
            vr0 = *reinterpret_cast<const int4*>(vbase + k0 + sc);
            vr1 = *reinterpret_cast<const int4*>(vbase + k0 + sc + 32);
        }
        __syncthreads();

        // K fragments once into registers, reused for both q-groups
        bf16x8 kf[2][4];
#pragma unroll
        for (int s = 0; s < 2; ++s)
#pragma unroll
            for (int ni = 0; ni < 4; ++ni)
                kf[s][ni] = *reinterpret_cast<const bf16x8*>(&sK[(ni * 16 + lr) * 72 + s * 32 + lq * 8]);

#pragma unroll
        for (int g = 0; g < 2; ++g) {
            f32x4 sf[4] = {};
#pragma unroll
            for (int s = 0; s < 2; ++s)
#pragma unroll
                for (int ni = 0; ni < 4; ++ni)
                    sf[ni] = __builtin_amdgcn_mfma_f32_16x16x32_bf16(qf[g][s], kf[s][ni], sf[ni], 0, 0, 0);

            if (useM) {
#pragma unroll
                for (int j = 0; j < 4; ++j) {
                    const int mr2 = (wave * 32 + g * 16 + lq * 4 + j) * 68;
#pragma unroll
                    for (int ni = 0; ni < 4; ++ni) {
                        const float mval = (float)sM[mr2 + ni * 16 + lr];
                        sP[wave][(g * 16 + lq * 4 + j) * 72 + ni * 16 + lr] = (bf16)exp2f(sf[ni][j] * SCL + mval);
                    }
                }
            } else {
#pragma unroll
                for (int j = 0; j < 4; ++j)
#pragma unroll
                    for (int ni = 0; ni < 4; ++ni)
                        sP[wave][(g * 16 + lq * 4 + j) * 72 + ni * 16 + lr] = (bf16)exp2f(sf[ni][j] * SCL);
            }
        }

        // V fragments once into registers, reused for both q-groups
        bf16x8 vf[2][4];
#pragma unroll
        for (int s = 0; s < 2; ++s)
#pragma unroll
            for (int ni = 0; ni < 4; ++ni)
                vf[s][ni] = *reinterpret_cast<const bf16x8*>(&sV[(ni * 16 + lr) * 72 + s * 32 + lq * 8]);

#pragma unroll
        for (int g = 0; g < 2; ++g) {
            f32x4 rs = {};
#pragma unroll
            for (int s = 0; s < 2; ++s) {
                bf16x8 pf = *reinterpret_cast<const bf16x8*>(&sP[wave][(g * 16 + lr) * 72 + s * 32 + lq * 8]);
                rs = __builtin_amdgcn_mfma_f32_16x16x32_bf16(pf, ones, rs, 0, 0, 0);
#pragma unroll
                for (int ni = 0; ni < 4; ++ni)
                    o[g][ni] = __builtin_amdgcn_mfma_f32_16x16x32_bf16(pf, vf[s][ni], o[g][ni], 0, 0, 0);
            }
#pragma unroll
            for (int j = 0; j < 4; ++j)
                lrow[g][j] += rs[j];
        }
    }

#pragma unroll
    for (int g = 0; g < 2; ++g)
#pragma unroll
        for (int ni = 0; ni < 4; ++ni)
#pragma unroll
            for (int j = 0; j < 4; ++j) {
                const int row = q0 + wave * 32 + g * 16 + lq * 4 + j;
                const int col = h * 64 + ni * 16 + lr;
                O[(size_t)(b * SEQ + row) * DIN + col] = (bf16)(o[g][ni][j] / lrow[g][j]);
            }
}

// ---------------------------------------------------------------------------
// Fused residual add + LayerNorm over D=512. X fp32, Y bf16.
// ---------------------------------------------------------------------------
__global__ __launch_bounds__(256) void add_ln(const float* __restrict__ X,
                                              const bf16* __restrict__ Y,
                                              bf16* __restrict__ Ob,
                                              float* __restrict__ Of)
{
    const int row  = blockIdx.x * 4 + (threadIdx.x >> 6);
    const int lane = threadIdx.x & 63;
    const size_t base = (size_t)row * DIN + lane * 8;
    const float4 x0 = *reinterpret_cast<const float4*>(X + base);
    const float4 x1 = *reinterpret_cast<const float4*>(X + base + 4);
    const bf16x8 yv = *reinterpret_cast<const bf16x8*>(Y + base);
    float v[8] = {x0.x, x0.y, x0.z, x0.w, x1.x, x1.y, x1.z, x1.w};
    float s = 0.f;
    for (int i = 0; i < 8; ++i) { v[i] += (float)yv[i]; s += v[i]; }
    for (int off = 1; off < 64; off <<= 1) s += __shfl_xor(s, off);
    const float mu = s * (1.f / DIN);
    float var = 0.f;
    for (int i = 0; i < 8; ++i) { const float d = v[i] - mu; var += d * d; }
    for (int off = 1; off < 64; off <<= 1) var += __shfl_xor(var, off);
    const float rstd = rsqrtf(var * (1.f / DIN) + 1e-5f);
    float r[8];
    for (int i = 0; i < 8; ++i) r[i] = (v[i] - mu) * rstd;
    if (Ob) {
        bf16x8 ov;
        for (int i = 0; i < 8; ++i) ov[i] = (bf16)r[i];
        *reinterpret_cast<bf16x8*>(Ob + base) = ov;
    }
    if (Of) {
        *reinterpret_cast<float4*>(Of + base)     = make_float4(r[0], r[1], r[2], r[3]);
        *reinterpret_cast<float4*>(Of + base + 4) = make_float4(r[4], r[5], r[6], r[7]);
    }
}

// ---------------------------------------------------------------------------
extern "C" void kernel_launch(void* const* d_in, const int* in_sizes, int n_in,
                              void* d_out, int out_size, void* d_ws, size_t ws_size,
                              hipStream_t stream)
{
    const float* query = (const float*)d_in[0];
    const float* key   = (const float*)d_in[1];
    const float* value = (const float*)d_in[2];
    const float* mask  = (const float*)d_in[3];
    const float* WQ    = (const float*)d_in[4];
    const float* WK    = (const float*)d_in[5];
    const float* WV    = (const float*)d_in[6];
    const float* WO    = (const float*)d_in[7];
    const float* W1    = (const float*)d_in[8];
    const float* W2    = (const float*)d_in[9];

    char* w = (char*)d_ws;
    size_t off = 0;
    auto carve2 = [&](size_t elems) { bf16* p = (bf16*)(w + off); off += elems * 2; return p; };
    auto carve4 = [&](size_t elems) { float* p = (float*)(w + off); off += elems * 4; return p; };

    bf16* Qb    = carve2((size_t)MROWS * DIN);
    bf16* Kb    = carve2((size_t)MROWS * DIN);
    bf16* Vb    = carve2((size_t)MROWS * DIN);
    bf16* Vt    = carve2((size_t)MROWS * DIN);
    bf16* Mid   = carve2((size_t)MROWS * DMID);
    float* Ln1f = carve4((size_t)MROWS * DIN);
    bf16* WQt   = carve2((size_t)DIN * DIN);
    bf16* WKt   = carve2((size_t)DIN * DIN);
    bf16* WVt   = carve2((size_t)DIN * DIN);
    bf16* WOt   = carve2((size_t)DIN * DIN);
    bf16* W1t   = carve2((size_t)DIN * DMID);
    bf16* W2t   = carve2((size_t)DMID * DIN);
    int*  mzf   = (int*)(w + off); off += 16;
    if (off > ws_size) return;

    // aliases of dead buffers:
    bf16* Ob   = Vb;   // attn output   (Vb dead after Vt transpose)
    bf16* Two  = Qb;   // WO output     (Qb dead after attention)
    bf16* Ln1b = Kb;   // LN1 bf16      (Kb dead after attention)
    bf16* F2   = Vt;   // FFN output    (Vt dead after attention)

    const dim3 blk(256);

    // mask-zero detection
    hipMemsetAsync(mzf, 0, 4, stream);
    mask_check<<<dim3(4096), blk, 0, stream>>>((const uint4*)mask, mzf);

    // all six weight cast+transposes in one launch
    transpose_weights<<<dim3(3072), blk, 0, stream>>>(WQ, WK, WV, WO, W1, W2,
                                                      WQt, WKt, WVt, WOt, W1t, W2t);

    // Q/K/V projections: 64x128-tile GEMM, fp32-A reg-staged, one launch
    gemm64_qkv<<<dim3(DIN / 128, MROWS / 64, 3), blk, 0, stream>>>(query, key, value,
                                                                   WQt, WKt, WVt, Qb, Kb, Vb);

    // V -> Vt[h*64+d][b*L+l]
    transpose_b2b<<<dim3(DIN / 32, MROWS / 32), blk, 0, stream>>>(Vb, Vt, DIN, MROWS);

    // attention (q-tile 128, 32 q-rows/wave, K/V frags reg-reused)
    attn_kernel<<<dim3(512), blk, 0, stream>>>(Qb, Kb, Vt, mask, Ob, mzf);

    // output projection + residual + LN (keep fp32 copy for residual 2)
    gemm64<0><<<dim3(DIN / 128, MROWS / 64), blk, 0, stream>>>(Ob, WOt, Two, DIN, DIN);
    add_ln<<<dim3(MROWS / 4), blk, 0, stream>>>(query, Two, Ln1b, Ln1f);

    // FFN
    gemm128<1><<<dim3(DMID / 128, MROWS / 128), blk, 0, stream>>>(Ln1b, W1t, Mid, DMID, DIN);
    gemm64<0><<<dim3(DIN / 128, MROWS / 64), blk, 0, stream>>>(Mid, W2t, F2, DIN, DMID);

    // final residual + LN -> fp32 output
    add_ln<<<dim3(MROWS / 4), blk, 0, stream>>>(Ln1f, F2, (bf16*)nullptr, (float*)d_out);
}